// Round 6
// baseline (640.815 us; speedup 1.0000x reference)
//
#include <hip/hip_runtime.h>

typedef __bf16 bf16x8 __attribute__((ext_vector_type(8)));
typedef float f32x4 __attribute__((ext_vector_type(4)));
typedef float f32x16 __attribute__((ext_vector_type(16)));

#define MFMA16(a, b, c) __builtin_amdgcn_mfma_f32_16x16x32_bf16(a, b, c, 0, 0, 0)
#define MFMA32(a, b, c) __builtin_amdgcn_mfma_f32_32x32x16_bf16(a, b, c, 0, 0, 0)
#define LOG2E 1.44269504088896340736f

__device__ __forceinline__ unsigned short f2bf(float f) {
  union { float f; unsigned u; } v; v.f = f;
  return (unsigned short)((v.u + 0x7fffu + ((v.u >> 16) & 1u)) >> 16);
}
__device__ __forceinline__ bf16x8 ld_frag(const unsigned short* p) {
  return *(const bf16x8*)p;  // 16B-aligned by construction
}
__device__ __forceinline__ void gld_lds16(const unsigned short* g, unsigned short* l) {
  __builtin_amdgcn_global_load_lds(
      (const __attribute__((address_space(1))) unsigned int*)(const void*)g,
      (__attribute__((address_space(3))) unsigned int*)(void*)l, 16, 0, 0);
}
// LDS-only barrier: does NOT drain vmcnt, so global loads stay in flight.
__device__ __forceinline__ void bar_lds() {
  asm volatile("s_waitcnt lgkmcnt(0)\ns_barrier" ::: "memory");
}

// fp32 -> bf16, 4 elements/thread
__global__ void cvt_f2bf(const float* __restrict__ in,
                         unsigned short* __restrict__ out, int n4) {
  int i = blockIdx.x * blockDim.x + threadIdx.x;
  if (i < n4) {
    float4 v = ((const float4*)in)[i];
    ushort4 o;
    o.x = f2bf(v.x); o.y = f2bf(v.y); o.z = f2bf(v.z); o.w = f2bf(v.w);
    ((ushort4*)out)[i] = o;
  }
}

// ---------------------------------------------------------------------------
// C[M,N] = A[M,K] * B[N,K]^T + bias[N]   (A,B bf16; bias fp32)
// mode 0: store fp32 to outf[M,N]
// mode 1: QKV split: n<512 -> qbuf; n<1024 -> kbuf; else transposed vtbuf[b][d][s]
// ---------------------------------------------------------------------------
__global__ void gemm_bt(const unsigned short* __restrict__ A,
                        const unsigned short* __restrict__ B,
                        const float* __restrict__ bias,
                        float* __restrict__ outf,
                        unsigned short* __restrict__ qbuf,
                        unsigned short* __restrict__ kbuf,
                        unsigned short* __restrict__ vtbuf,
                        int M, int N, int K, int mode) {
  __shared__ alignas(16) unsigned short As[128 * 32];
  __shared__ alignas(16) unsigned short Bs[128 * 32];
  const int n0 = blockIdx.x * 128, m0 = blockIdx.y * 128;
  const int tid = threadIdx.x;
  const int l = tid & 63, w = tid >> 6;
  const int quad = l >> 4, c = l & 15;
  const int wm = (w >> 1) * 64, wn = (w & 1) * 64;

  f32x4 acc[4][4] = {};
  const int kiters = K >> 5;
  for (int kt = 0; kt < kiters; ++kt) {
    __syncthreads();
    const int kk = kt * 32 + (l & 3) * 8;
    const int row = l >> 2;
#pragma unroll
    for (int i = 0; i < 2; ++i) {
      const int rbase = i * 64 + w * 16;
      gld_lds16(&A[(size_t)(m0 + rbase + row) * K + kk], &As[rbase * 32]);
      gld_lds16(&B[(size_t)(n0 + rbase + row) * K + kk], &Bs[rbase * 32]);
    }
    __syncthreads();
    bf16x8 af[4], bfr[4];
#pragma unroll
    for (int t = 0; t < 4; ++t) {
      af[t] = ld_frag(&As[(wm + t * 16 + c) * 32 + quad * 8]);
      bfr[t] = ld_frag(&Bs[(wn + t * 16 + c) * 32 + quad * 8]);
    }
#pragma unroll
    for (int mt = 0; mt < 4; ++mt)
#pragma unroll
      for (int nt = 0; nt < 4; ++nt)
        acc[mt][nt] = MFMA16(af[mt], bfr[nt], acc[mt][nt]);
  }

#pragma unroll
  for (int nt = 0; nt < 4; ++nt) {
    const int n = n0 + wn + nt * 16 + c;
    const float bsum = bias[n];
#pragma unroll
    for (int mt = 0; mt < 4; ++mt) {
      const int mbase = m0 + wm + mt * 16 + quad * 4;
      if (mode == 0) {
#pragma unroll
        for (int r = 0; r < 4; ++r)
          outf[(size_t)(mbase + r) * N + n] = acc[mt][nt][r] + bsum;
      } else if (n < 1024) {
        unsigned short* dst = (n < 512) ? qbuf : kbuf;
        const int nn = n & 511;
#pragma unroll
        for (int r = 0; r < 4; ++r)
          dst[(size_t)(mbase + r) * 512 + nn] = f2bf(acc[mt][nt][r] + bsum);
      } else {
        const int d = n - 1024;
        const int bb = mbase >> 12, s = mbase & 4095;
        ushort4 pk;
        pk.x = f2bf(acc[mt][nt][0] + bsum);
        pk.y = f2bf(acc[mt][nt][1] + bsum);
        pk.z = f2bf(acc[mt][nt][2] + bsum);
        pk.w = f2bf(acc[mt][nt][3] + bsum);
        *(ushort4*)&vtbuf[((size_t)bb * 512 + d) * 4096 + s] = pk;
      }
    }
  }
}

// ---------------------------------------------------------------------------
// Flash attention, stage-free: MFMA A/B fragments loaded DIRECTLY from
// global (L2/L3-served; zero intra-block reuse makes LDS staging pure
// overhead). 32x32x16 MFMA, transposed-S.
// Grid 512 = 4b x 128 qt (XCD-pinned); block = 32 q x 4096 kv, 64 iters of 64.
// Waves: S^T wave(kvh,kh2) = [32kv x 32q] partial over K-half (f32 LDS
// exchange with partner w^1); PV wave w owns d-range w*128 (o[4] f32x16).
// LDS only: exchange 16KB + P^T 4.5KB + m/l broadcast. 2 blocks/CU.
// ---------------------------------------------------------------------------
#define PROW 72

__global__ __launch_bounds__(256, 2) void attn_kernel(
    const unsigned short* __restrict__ Q, const unsigned short* __restrict__ Kb,
    const unsigned short* __restrict__ Vt, unsigned short* __restrict__ O) {
  __shared__ alignas(16) float ex[4 * 64 * 16];            // 16 KB
  __shared__ alignas(16) unsigned short p_lds[32 * PROW];  // 4.5 KB
  __shared__ float mml[64];
  __shared__ float lml[64];

  const int bid = blockIdx.x;
  const int xcd = bid & 7;
  const int b = xcd >> 1;                        // 2 XCDs per batch
  const int qt = (bid >> 3) | ((xcd & 1) << 6);  // 0..127
  const int s0 = qt * 32;
  const int tid = threadIdx.x;
  const int l = tid & 63, w = tid >> 6;
  const int kvh = w >> 1, kh2 = w & 1;
  const int l31 = l & 31, h = l >> 5;
  const size_t boff = (size_t)b * 4096 * 512;

  // Q frags pinned: B-operand, q = s0+l31, k = kh2*256 + t*16 + h*8 + j
  bf16x8 qf[16];
  {
    const unsigned short* qrow =
        Q + boff + (size_t)(s0 + l31) * 512 + kh2 * 256 + h * 8;
#pragma unroll
    for (int t = 0; t < 16; ++t) qf[t] = ld_frag(&qrow[t * 16]);
  }

  f32x16 o[4] = {};  // O^T: d = w*128 + dt*32 + (r&3)+8*(r>>2)+4h ; q = l31
  float m_run = -3e38f, l_run = 0.f;

  // per-wave global fragment base pointers
  const unsigned short* Kwave =
      Kb + boff + (size_t)(kvh * 32 + l31) * 512 + kh2 * 256 + h * 8;
  const unsigned short* Vbase = Vt + (size_t)b * 512 * 4096;
  const unsigned short* vrow[4];
#pragma unroll
  for (int dt = 0; dt < 4; ++dt)
    vrow[dt] = Vbase + (size_t)(w * 128 + dt * 32 + l31) * 4096 + h * 8;

  const float C1 = 0.125f * LOG2E;

  for (int it = 0; it < 64; ++it) {
    const int kv0 = it * 64;

    // S^T partial over K-half: A = K frag (direct global), B = Q frag (regs)
    const unsigned short* kp = Kwave + (size_t)kv0 * 512;
    bf16x8 kf[16];
#pragma unroll
    for (int t = 0; t < 16; ++t) kf[t] = ld_frag(&kp[t * 16]);
    f32x16 a0 = {}, a1 = {};
#pragma unroll
    for (int t = 0; t < 16; t += 2) {
      a0 = MFMA32(kf[t], qf[t], a0);
      a1 = MFMA32(kf[t + 1], qf[t + 1], a1);
    }
    f32x16 ss = a0 + a1;

    // V frag loads issue now; consumed after 3 barriers (vmcnt not drained)
    bf16x8 vf[16];
#pragma unroll
    for (int dt = 0; dt < 4; ++dt)
#pragma unroll
      for (int kc = 0; kc < 4; ++kc)
        vf[dt * 4 + kc] = ld_frag(&vrow[dt][kv0 + kc * 16]);

    // exchange S-partial with K-half partner (w^1), sum
    {
      float* exw = &ex[(w * 64 + l) * 16];
#pragma unroll
      for (int r = 0; r < 16; r += 4) {
        f32x4 t4; t4[0] = ss[r]; t4[1] = ss[r + 1]; t4[2] = ss[r + 2]; t4[3] = ss[r + 3];
        *(f32x4*)&exw[r] = t4;
      }
    }
    bar_lds();
    {
      const float* exp_ = &ex[((w ^ 1) * 64 + l) * 16];
#pragma unroll
      for (int r = 0; r < 16; r += 4) {
        f32x4 t4 = *(const f32x4*)&exp_[r];
        ss[r] += t4[0]; ss[r + 1] += t4[1]; ss[r + 2] += t4[2]; ss[r + 3] += t4[3];
      }
    }

    // block max: in-lane 16 + cross-h shuffle + cross-kvh via LDS
    float mloc = ss[0];
#pragma unroll
    for (int r = 1; r < 16; ++r) mloc = fmaxf(mloc, ss[r]);
    mloc = fmaxf(mloc, __shfl_xor(mloc, 32));
    if (kh2 == 0 && l < 32) mml[kvh * 32 + l] = mloc;
    bar_lds();
    const float mn = fmaxf(m_run, fmaxf(mml[l31], mml[32 + l31]));

    float p[16], s8 = 0.f;
#pragma unroll
    for (int r = 0; r < 16; ++r) {
      p[r] = exp2f((ss[r] - mn) * C1);
      s8 += p[r];
    }
    s8 += __shfl_xor(s8, 32);

    // P^T write: wave's kh2 half of its kvh tile (kv = kvh*32+kh2*16+..)
    {
      unsigned short* pr = &p_lds[l31 * PROW + kvh * 32 + kh2 * 16 + 4 * h];
      const int rb = kh2 * 8;
      ushort4 u0, u1;
      u0.x = f2bf(p[rb + 0]); u0.y = f2bf(p[rb + 1]);
      u0.z = f2bf(p[rb + 2]); u0.w = f2bf(p[rb + 3]);
      u1.x = f2bf(p[rb + 4]); u1.y = f2bf(p[rb + 5]);
      u1.z = f2bf(p[rb + 6]); u1.w = f2bf(p[rb + 7]);
      *(ushort4*)&pr[0] = u0;
      *(ushort4*)&pr[8] = u1;
    }

    if (__any(mn > m_run)) {
      const float alpha = exp2f((m_run - mn) * C1);
      l_run = l_run * alpha + s8;
      m_run = mn;
#pragma unroll
      for (int dt = 0; dt < 4; ++dt)
#pragma unroll
        for (int e = 0; e < 16; ++e) o[dt][e] *= alpha;
    } else {
      l_run += s8;
    }
    bar_lds();

    // O^T += V^T P^T : A = V frag (global, already in flight), B = P frag
    bf16x8 pf[4];
#pragma unroll
    for (int kc = 0; kc < 4; ++kc)
      pf[kc] = ld_frag(&p_lds[l31 * PROW + kc * 16 + h * 8]);
#pragma unroll
    for (int kc = 0; kc < 4; ++kc)
#pragma unroll
      for (int dt = 0; dt < 4; ++dt)
        o[dt] = MFMA32(vf[dt * 4 + kc], pf[kc], o[dt]);
  }

  // epilogue: combine l across the two kv streams, normalize, store
  if (kh2 == 0 && l < 32) lml[kvh * 32 + l] = l_run;
  bar_lds();
  const float inv = 1.0f / (lml[l31] + lml[32 + l31]);
  unsigned short* orow = O + boff + (size_t)(s0 + l31) * 512 + w * 128 + 4 * h;
#pragma unroll
  for (int dt = 0; dt < 4; ++dt)
#pragma unroll
    for (int g = 0; g < 4; ++g) {
      ushort4 pk;
      pk.x = f2bf(o[dt][g * 4 + 0] * inv);
      pk.y = f2bf(o[dt][g * 4 + 1] * inv);
      pk.z = f2bf(o[dt][g * 4 + 2] * inv);
      pk.w = f2bf(o[dt][g * 4 + 3] * inv);
      *(ushort4*)&orow[dt * 32 + g * 8] = pk;
    }
}

// ---------------------------------------------------------------------------
extern "C" void kernel_launch(void* const* d_in, const int* in_sizes, int n_in,
                              void* d_out, int out_size, void* d_ws, size_t ws_size,
                              hipStream_t stream) {
  const float* x = (const float*)d_in[0];      // [4,4096,512] fp32
  const float* w_in = (const float*)d_in[1];   // [1536,512] fp32
  const float* b_in = (const float*)d_in[2];   // [1536] fp32
  const float* w_out = (const float*)d_in[3];  // [512,512] fp32
  const float* b_out = (const float*)d_in[4];  // [512] fp32
  float* out = (float*)d_out;                  // [4,4096,512] fp32

  const size_t MTOT = (size_t)4 * 4096 * 512;  // 8,388,608
  unsigned short* q = (unsigned short*)d_ws;
  unsigned short* k = q + MTOT;
  unsigned short* vt = k + MTOT;    // [b][d][s]
  unsigned short* xbf = vt + MTOT;  // x bf16 -> attn output (x dead after gemm1)
  unsigned short* w_in_bf = xbf + MTOT;
  unsigned short* w_out_bf = w_in_bf + 1536 * 512;

  cvt_f2bf<<<dim3((int)(MTOT / 4 / 256)), 256, 0, stream>>>(x, xbf,
                                                            (int)(MTOT / 4));
  cvt_f2bf<<<dim3(768), 256, 0, stream>>>(w_in, w_in_bf, 1536 * 512 / 4);
  cvt_f2bf<<<dim3(256), 256, 0, stream>>>(w_out, w_out_bf, 512 * 512 / 4);

  gemm_bt<<<dim3(12, 128), 256, 0, stream>>>(xbf, w_in_bf, b_in, nullptr, q, k,
                                             vt, 16384, 1536, 512, 1);
  attn_kernel<<<dim3(512), 256, 0, stream>>>(q, k, vt, xbf);
  gemm_bt<<<dim3(4, 128), 256, 0, stream>>>(xbf, w_out_bf, b_out, out, nullptr,
                                            nullptr, nullptr, 16384, 512, 512,
                                            0);
}